// Round 2
// baseline (60233.893 us; speedup 1.0000x reference)
//
#include <hip/hip_runtime.h>

typedef _Float16 f16;
typedef f16 f16x2 __attribute__((ext_vector_type(2)));
typedef f16 f16x8 __attribute__((ext_vector_type(8)));
typedef float f32x4 __attribute__((ext_vector_type(4)));

#define TT 1024
#define BB 32
#define DD 1024
#define RR 256
#define QR 64            // r-rows per quarter WG
#define NQ 4             // WGs per batch

__device__ __forceinline__ float dot2f(f16x2 a, f16x2 b, float c) {
#if __has_builtin(__builtin_amdgcn_fdot2)
    return __builtin_amdgcn_fdot2(a, b, c, false);
#else
    return c + (float)a[0] * (float)b[0] + (float)a[1] * (float)b[1];
#endif
}

__device__ __forceinline__ float sigm_f(float x) { return 1.0f / (1.0f + __expf(-x)); }
__device__ __forceinline__ float tanh_f(float x) { return 1.0f - 2.0f / (1.0f + __expf(2.0f * x)); }

// ---------------------------------------------------------------------------
// Kernel 1: fused pre-GEMM (unchanged from round 1 — ~230 TF, not the
// bottleneck this round).  ax = x@Wa^T + ba ; wx = x@Wx^T + b, f16 out.
// ---------------------------------------------------------------------------
__global__ __launch_bounds__(256)
void fused_pregemm(const float* __restrict__ X, const float* __restrict__ Wa,
                   const float* __restrict__ Wx, const float* __restrict__ ba,
                   const float* __restrict__ bb, f16* __restrict__ axo,
                   f16* __restrict__ wxo)
{
    __shared__ __align__(16) f16 lA[64][40];
    __shared__ __align__(16) f16 lB[64][40];
    __shared__ __align__(16) f16 lC[64][40];

    const int tid = threadIdx.x;
    const int w   = tid >> 6;
    const int l   = tid & 63;
    const int la  = l & 15;
    const int qd  = l >> 4;
    const int m0  = blockIdx.x * 64;
    const int n0  = blockIdx.y * 64;
    const int sr  = tid >> 2;
    const int sk  = (tid & 3) * 8;

    f32x4 accA[4] = {};
    f32x4 accX[4] = {};

    for (int k0 = 0; k0 < DD; k0 += 32) {
        {
            const float* pX = X + (size_t)(m0 + sr) * DD + k0 + sk;
            float4 v0 = *(const float4*)pX;
            float4 v1 = *(const float4*)(pX + 4);
            f16x8 x8 = {(f16)v0.x, (f16)v0.y, (f16)v0.z, (f16)v0.w,
                        (f16)v1.x, (f16)v1.y, (f16)v1.z, (f16)v1.w};
            *(f16x8*)&lA[sr][sk] = x8;

            const float* pA = Wa + (size_t)(n0 + sr) * DD + k0 + sk;
            v0 = *(const float4*)pA;
            v1 = *(const float4*)(pA + 4);
            f16x8 a8 = {(f16)v0.x, (f16)v0.y, (f16)v0.z, (f16)v0.w,
                        (f16)v1.x, (f16)v1.y, (f16)v1.z, (f16)v1.w};
            *(f16x8*)&lB[sr][sk] = a8;

            const float* pW = Wx + (size_t)(n0 + sr) * DD + k0 + sk;
            v0 = *(const float4*)pW;
            v1 = *(const float4*)(pW + 4);
            f16x8 w8 = {(f16)v0.x, (f16)v0.y, (f16)v0.z, (f16)v0.w,
                        (f16)v1.x, (f16)v1.y, (f16)v1.z, (f16)v1.w};
            *(f16x8*)&lC[sr][sk] = w8;
        }
        __syncthreads();

        f16x8 af = *(const f16x8*)&lA[16 * w + la][qd * 8];
        #pragma unroll
        for (int c = 0; c < 4; c++) {
            f16x8 b1 = *(const f16x8*)&lB[16 * c + la][qd * 8];
            f16x8 b2 = *(const f16x8*)&lC[16 * c + la][qd * 8];
            accA[c] = __builtin_amdgcn_mfma_f32_16x16x32_f16(af, b1, accA[c], 0, 0, 0);
            accX[c] = __builtin_amdgcn_mfma_f32_16x16x32_f16(af, b2, accX[c], 0, 0, 0);
        }
        __syncthreads();
    }

    #pragma unroll
    for (int c = 0; c < 4; c++) {
        const int n = n0 + 16 * c + la;
        const float bav = ba[n];
        const float bbv = bb[n];
        #pragma unroll
        for (int r = 0; r < 4; r++) {
            const int m = m0 + 16 * w + qd * 4 + r;
            axo[(size_t)m * DD + n] = (f16)(accA[c][r] + bav);
            wxo[(size_t)m * DD + n] = (f16)(accX[c][r] + bbv);
        }
    }
}

// ---------------------------------------------------------------------------
// Flag init: d_ws is re-poisoned 0xAA before every timed call, so the
// cross-WG sync flags must be zeroed at the start of every launch.
// ---------------------------------------------------------------------------
__global__ void zero_flags(unsigned* __restrict__ flags) {
    flags[threadIdx.x] = 0;
}

// ---------------------------------------------------------------------------
// Kernel 2: scan, 4-way R-split.  128 WGs x 1024 threads; WG w serves batch
// b=w>>2, quarter q=w&3 (rows q*64..q*64+64 of V, cols q*64.. of U).
// Per-thread weights: V[q*64+(tid&63)][ (tid>>6)*64 +: 64 ] (32 VGPRs) and
// U[tid][q*64 +: 64] (32 VGPRs) -> 64 weight VGPRs, fits the 128-VGPR cap
// at 1024 threads (round-1 spill root cause fixed).
// Each WG redundantly maintains the full h[1024] for its batch; only the
// rank-64 u-partial crosses WGs, via release-store flag / acquire-poll with
// AGENT scope (handles cross-XCD L2 writeback/invalidate).
// ---------------------------------------------------------------------------
__global__ __launch_bounds__(1024, 4)
void rnn_scan4(const f16* __restrict__ ax, const f16* __restrict__ wx,
               const float* __restrict__ V, const float* __restrict__ U,
               const float* __restrict__ h0, float* __restrict__ out,
               float* __restrict__ hout, float* __restrict__ ubuf,
               unsigned* __restrict__ flags)
{
    const int w   = blockIdx.x;     // 0..127
    const int b   = w >> 2;
    const int q   = w & 3;
    const int b4  = b << 2;
    const int tid = threadIdx.x;
    const int rl  = tid & 63;       // stage1: my r within quarter
    const int ds  = tid >> 6;       // stage1: my d-slice (64 d) == wave id

    __shared__ __align__(16) f16 h2[DD];     // h as f16 (matvec input)
    __shared__ float hf[DD];                 // h as f32 (blend path)
    __shared__ float part[16][QR];           // stage1 partials [slice][r]
    __shared__ __align__(16) f16 pl[QR];     // p quarter as f16

    // ---- weights -> registers (one-time)
    f16x2 wv1[32];
    {
        const float2* vp = (const float2*)(V + (size_t)(q * QR + rl) * DD + ds * 64);
        #pragma unroll
        for (int i = 0; i < 32; i++) {
            float2 tv = vp[i];
            f16x2 p2 = {(f16)tv.x, (f16)tv.y};
            wv1[i] = p2;
        }
    }
    f16x2 wu1[32];
    {
        const float2* up2 = (const float2*)(U + (size_t)tid * RR + q * QR);
        #pragma unroll
        for (int i = 0; i < 32; i++) {
            float2 tu = up2[i];
            f16x2 p2 = {(f16)tu.x, (f16)tu.y};
            wu1[i] = p2;
        }
    }

    // ---- init h; emit h[0]
    const float h0v = h0[(size_t)b * DD + tid];
    hf[tid] = h0v;
    h2[tid] = (f16)h0v;
    if ((tid >> 8) == q) hout[(size_t)b * DD + tid] = h0v;

    const f16* axp   = ax  + (size_t)b * DD + tid;
    const f16* wxp   = wx  + (size_t)b * DD + tid;
    float*     outp  = out + (size_t)b * DD + tid;
    float*     houtp = hout + (size_t)BB * DD + (size_t)b * DD + tid;

    float* myu = ubuf + ((size_t)w * 2) * 1024;

    __syncthreads();

    #pragma unroll 1
    for (int t = 0; t < TT; t++) {
        // prefetch this step's gate inputs (consumed in elementwise; hides
        // global latency under stage1/stage2 VALU)
        const float axv = (float)*axp;
        const float wxv = (float)*wxp;

        // ---- stage 1: partial p[q*64+rl] over my 64-d slice
        const f16x8* hsl = (const f16x8*)(h2 + ds * 64);
        float acc = 0.f;
        #pragma unroll
        for (int i = 0; i < 8; i++) {
            f16x8 hv = hsl[i];
            f16x2 hp0 = {hv[0], hv[1]}, hp1 = {hv[2], hv[3]};
            f16x2 hp2 = {hv[4], hv[5]}, hp3 = {hv[6], hv[7]};
            acc = dot2f(wv1[4 * i + 0], hp0, acc);
            acc = dot2f(wv1[4 * i + 1], hp1, acc);
            acc = dot2f(wv1[4 * i + 2], hp2, acc);
            acc = dot2f(wv1[4 * i + 3], hp3, acc);
        }
        part[ds][rl] = acc;
        __syncthreads();

        // ---- reduce 16 slices -> p quarter, pack f16
        if (tid < QR) {
            float pv = 0.f;
            #pragma unroll
            for (int ss = 0; ss < 16; ss++) pv += part[ss][tid];
            pl[tid] = (f16)pv;
        }
        __syncthreads();

        // ---- stage 2: u-partial for e=tid over my 64 r's (pl broadcast)
        const f16x8* psl = (const f16x8*)pl;
        float ua = 0.f;
        #pragma unroll
        for (int i = 0; i < 8; i++) {
            f16x8 pv8 = psl[i];
            f16x2 pp0 = {pv8[0], pv8[1]}, pp1 = {pv8[2], pv8[3]};
            f16x2 pp2 = {pv8[4], pv8[5]}, pp3 = {pv8[6], pv8[7]};
            ua = dot2f(wu1[4 * i + 0], pp0, ua);
            ua = dot2f(wu1[4 * i + 1], pp1, ua);
            ua = dot2f(wu1[4 * i + 2], pp2, ua);
            ua = dot2f(wu1[4 * i + 3], pp3, ua);
        }

        // ---- post my u-partial (double-buffered by t parity)
        const int slot = t & 1;
        myu[slot * 1024 + tid] = ua;
        __syncthreads();   // all waves' stores drained to L2 before release
        if (tid == 0)
            __hip_atomic_store(&flags[w], (unsigned)(t + 1),
                               __ATOMIC_RELEASE, __HIP_MEMORY_SCOPE_AGENT);

        // ---- poll the 3 partner quarters (lane 0 of each wave; acquire on
        // success invalidates L1 + XCD-L2 so the plain gather loads below
        // refetch from the coherence point)
        const unsigned need = (unsigned)(t + 1);
        #pragma unroll
        for (int j = 1; j < NQ; j++) {
            const int pw = b4 + ((q + j) & 3);
            if ((tid & 63) == 0) {
                while (__hip_atomic_load(&flags[pw], __ATOMIC_ACQUIRE,
                                         __HIP_MEMORY_SCOPE_AGENT) < need)
                    __builtin_amdgcn_s_sleep(1);
            }
        }

        // ---- gather + elementwise (every WG keeps full h)
        float ut = ua;
        #pragma unroll
        for (int j = 1; j < NQ; j++) {
            const int pw = b4 + ((q + j) & 3);
            ut += ubuf[((size_t)pw * 2 + slot) * 1024 + tid];
        }
        {
            const float uu = ut + wxv;
            const float vv = tanh_f(uu);
            const float aa = sigm_f(axv);
            const float hp = hf[tid];
            const float hn = aa * hp + (1.0f - aa) * vv;
            hf[tid] = hn;
            h2[tid] = (f16)hn;
            if ((tid >> 8) == q) {
                *outp  = hn * hn * sigm_f(hn);   // h * silu(h)
                *houtp = hn;
            }
        }
        axp += BB * DD; wxp += BB * DD; outp += BB * DD; houtp += BB * DD;
        __syncthreads();   // h2/hf published before next stage 1
    }
}

extern "C" void kernel_launch(void* const* d_in, const int* in_sizes, int n_in,
                              void* d_out, int out_size, void* d_ws, size_t ws_size,
                              hipStream_t stream) {
    (void)in_sizes; (void)n_in; (void)out_size; (void)ws_size;
    const float* x  = (const float*)d_in[0];
    const float* h0 = (const float*)d_in[1];
    const float* Wa = (const float*)d_in[2];
    const float* ba = (const float*)d_in[3];
    const float* U  = (const float*)d_in[4];
    const float* V  = (const float*)d_in[5];
    const float* Wx = (const float*)d_in[6];
    const float* bb = (const float*)d_in[7];

    float* out  = (float*)d_out;                    // output [T,B,D]
    float* hout = out + (size_t)TT * BB * DD;       // h [T+1,B,D]

    f16* ax16 = (f16*)d_ws;                         // 64 MiB
    f16* wx16 = ax16 + (size_t)TT * BB * DD;        // 64 MiB
    float* ubuf = (float*)(wx16 + (size_t)TT * BB * DD);   // 128 WG x 2 slots x 1024 f32 = 1 MiB
    unsigned* flags = (unsigned*)(ubuf + (size_t)BB * NQ * 2 * 1024);  // 128 u32

    dim3 g1(512, 16);
    fused_pregemm<<<g1, dim3(256), 0, stream>>>(x, Wa, Wx, ba, bb, ax16, wx16);
    zero_flags<<<dim3(1), dim3(BB * NQ), 0, stream>>>(flags);
    rnn_scan4<<<dim3(BB * NQ), dim3(1024), 0, stream>>>(ax16, wx16, V, U, h0,
                                                        out, hout, ubuf, flags);
}